// Round 1
// baseline (197.207 us; speedup 1.0000x reference)
//
#include <hip/hip_runtime.h>
#include <hip/hip_bf16.h>

// Problem constants
#define BB 16
#define SS 1024
#define DD 384
#define HH 6
#define HDD 64
#define KK 9
#define KH 54      // K*H
#define OUTD 384
#define TT 8       // seq positions per conv block

typedef __attribute__((ext_vector_type(4))) float floatx4;
typedef __attribute__((ext_vector_type(8))) __bf16 bf16x8;

// ---------------------------------------------------------------------------
// Kernel 0: cast Wp (f32) -> bf16 in workspace
// ---------------------------------------------------------------------------
__global__ __launch_bounds__(256) void cast_wp_kernel(const float* __restrict__ Wp,
                                                      __hip_bfloat16* __restrict__ WpB) {
    int i = blockIdx.x * 256 + threadIdx.x;
    if (i < OUTD * DD) WpB[i] = __float2bfloat16(Wp[i]);
}

// ---------------------------------------------------------------------------
// Kernel 1: fused (q*ks)@Wk^T + bk -> softmax over taps -> 9-tap dynamic conv
// One block (256 threads) handles TT=8 consecutive seq positions of one batch.
// Writes conv output as bf16 activation matrix A[16384][384].
// ---------------------------------------------------------------------------
__global__ __launch_bounds__(256) void conv_kernel(const float* __restrict__ q,
                                                   const float* __restrict__ ks,
                                                   const float* __restrict__ v,
                                                   const float* __restrict__ Wk,
                                                   const float* __restrict__ bk,
                                                   __hip_bfloat16* __restrict__ outA) {
    __shared__ float qk[TT * DD];           // 3072 f  (12 KB)
    __shared__ float win[(TT + 8) * DD];    // 6144 f  (24 KB)
    __shared__ float plog[KH * 4 * 9];      // partials [o][part] stride 9, idx t (7.8 KB)
    __shared__ float dk[TT * KH];           // softmaxed taps (1.7 KB)

    const int blk = blockIdx.x;
    const int b   = blk / (SS / TT);        // SS/TT = 128 blocks per batch
    const int s0  = (blk % (SS / TT)) * TT;
    const int tid = threadIdx.x;

    // --- stage qk = q*ks for 8 positions (contiguous 3072 floats) ---
    const float* qb = q  + ((size_t)b * SS + s0) * DD;
    const float* kb = ks + ((size_t)b * SS + s0) * DD;
    for (int i = tid; i < TT * DD; i += 256) qk[i] = qb[i] * kb[i];

    // --- stage v window rows s0-4 .. s0+11 (zero-padded) ---
    const float* vb = v + (size_t)b * SS * DD;
    for (int i = tid; i < (TT + 8) * DD; i += 256) {
        int r = s0 - 4 + i / DD;
        int d = i % DD;
        win[i] = (r >= 0 && r < SS) ? vb[(size_t)r * DD + d] : 0.0f;
    }
    __syncthreads();

    // --- logits partials: thread = (part, o), part covers 96 d's, all 8 t's ---
    if (tid < 216) {
        int o = tid % KH, part = tid / KH;   // lanes with same part have consecutive o
        float acc[TT];
#pragma unroll
        for (int t = 0; t < TT; ++t) acc[t] = 0.0f;
        const float* wrow = Wk + (size_t)o * DD + part * 96;
        const float* qkp  = qk + part * 96;
        for (int j = 0; j < 96; ++j) {
            float w = wrow[j];
#pragma unroll
            for (int t = 0; t < TT; ++t) acc[t] += w * qkp[t * DD + j];
        }
#pragma unroll
        for (int t = 0; t < TT; ++t) plog[(o * 4 + part) * 9 + t] = acc[t];
    }
    __syncthreads();

    // --- reduce partials + softmax over K taps: thread per (t, h) ---
    if (tid < TT * HH) {
        int t = tid / HH, h = tid % HH;
        float lg[KK];
        float mx = -1e30f;
#pragma unroll
        for (int k = 0; k < KK; ++k) {
            int o = h * KK + k;
            float s = bk[o];
#pragma unroll
            for (int p = 0; p < 4; ++p) s += plog[(o * 4 + p) * 9 + t];
            lg[k] = s;
            mx = fmaxf(mx, s);
        }
        float sum = 0.0f;
#pragma unroll
        for (int k = 0; k < KK; ++k) { lg[k] = __expf(lg[k] - mx); sum += lg[k]; }
        float inv = 1.0f / sum;
#pragma unroll
        for (int k = 0; k < KK; ++k) dk[t * KH + h * KK + k] = lg[k] * inv;
    }
    __syncthreads();

    // --- 9-tap conv, write bf16 ---
    __hip_bfloat16* orow = outA + ((size_t)b * SS + s0) * DD;
    for (int i = tid; i < TT * DD; i += 256) {
        int t = i / DD, d = i % DD, h = d >> 6;
        float acc = 0.0f;
#pragma unroll
        for (int k = 0; k < KK; ++k)
            acc += win[(t + k) * DD + d] * dk[t * KH + h * KK + k];
        orow[i] = __float2bfloat16(acc);
    }
}

// ---------------------------------------------------------------------------
// Kernel 2: C[16384][384] = A[16384][384](bf16) @ Wp[384][384]^T(bf16) + bp
// 128x64 block tile, BK=32, 4 waves (2x2), mfma_f32_16x16x32_bf16.
// ---------------------------------------------------------------------------
#define BM 128
#define BN 64
#define BK 32
#define LDA 40   // BK + 8 pad (bf16 elems): bank stride 20 -> <=2-way conflicts

__global__ __launch_bounds__(256) void gemm_kernel(const unsigned short* __restrict__ A,
                                                   const unsigned short* __restrict__ Bw,
                                                   const float* __restrict__ bias,
                                                   float* __restrict__ Cout) {
    __shared__ unsigned short As[BM * LDA];   // 10 KB
    __shared__ unsigned short Bs[BN * LDA];   // 5 KB

    const int tid  = threadIdx.x;
    const int wave = tid >> 6;
    const int lane = tid & 63;

    const int mtile = blockIdx.x / (OUTD / BN);   // 6 ntiles
    const int ntile = blockIdx.x % (OUTD / BN);
    const int m0 = mtile * BM;
    const int n0 = ntile * BN;

    const int wm = (wave >> 1) * 64;  // wave row offset within tile
    const int wn = (wave & 1) * 32;   // wave col offset within tile

    floatx4 acc[4][2] = {};

    const int fr = lane & 15;           // m (A) / n (B) within 16
    const int fk = (lane >> 4) * 8;     // k offset within 32

    for (int k0 = 0; k0 < DD; k0 += BK) {
        // stage A: 128 rows x 32 cols, 16B per thread x 2 passes
#pragma unroll
        for (int p = 0; p < 2; ++p) {
            int c = tid + p * 256;
            int r = c >> 2, cg = (c & 3) * 8;
            *reinterpret_cast<uint4*>(&As[r * LDA + cg]) =
                *reinterpret_cast<const uint4*>(A + (size_t)(m0 + r) * DD + k0 + cg);
        }
        // stage B: 64 rows x 32 cols, 16B per thread
        {
            int r = tid >> 2, cg = (tid & 3) * 8;
            *reinterpret_cast<uint4*>(&Bs[r * LDA + cg]) =
                *reinterpret_cast<const uint4*>(Bw + (size_t)(n0 + r) * DD + k0 + cg);
        }
        __syncthreads();

        bf16x8 bfrag[2];
#pragma unroll
        for (int j = 0; j < 2; ++j)
            bfrag[j] = *reinterpret_cast<const bf16x8*>(&Bs[(wn + j * 16 + fr) * LDA + fk]);
#pragma unroll
        for (int i = 0; i < 4; ++i) {
            bf16x8 afrag = *reinterpret_cast<const bf16x8*>(&As[(wm + i * 16 + fr) * LDA + fk]);
#pragma unroll
            for (int j = 0; j < 2; ++j)
                acc[i][j] = __builtin_amdgcn_mfma_f32_16x16x32_bf16(afrag, bfrag[j], acc[i][j], 0, 0, 0);
        }
        __syncthreads();
    }

    // epilogue: C/D layout col=lane&15, row=(lane>>4)*4+reg
    const int col_in = lane & 15;
    const int rgrp   = (lane >> 4) * 4;
#pragma unroll
    for (int i = 0; i < 4; ++i) {
#pragma unroll
        for (int j = 0; j < 2; ++j) {
            int col = n0 + wn + j * 16 + col_in;
            float bv = bias[col];
#pragma unroll
            for (int r = 0; r < 4; ++r) {
                int row = m0 + wm + i * 16 + rgrp + r;
                Cout[(size_t)row * OUTD + col] = acc[i][j][r] + bv;
            }
        }
    }
}

// ---------------------------------------------------------------------------
extern "C" void kernel_launch(void* const* d_in, const int* in_sizes, int n_in,
                              void* d_out, int out_size, void* d_ws, size_t ws_size,
                              hipStream_t stream) {
    const float* q  = (const float*)d_in[0];
    const float* ks = (const float*)d_in[1];
    const float* v  = (const float*)d_in[2];
    const float* Wk = (const float*)d_in[3];
    const float* bk = (const float*)d_in[4];
    const float* Wp = (const float*)d_in[5];
    const float* bp = (const float*)d_in[6];
    float* out = (float*)d_out;

    // workspace layout: [WpB bf16: 384*384*2 = 294912 B][A bf16: 16384*384*2 = 12.6 MB]
    __hip_bfloat16* WpB = (__hip_bfloat16*)d_ws;
    __hip_bfloat16* Abf = (__hip_bfloat16*)((char*)d_ws + 294912);

    cast_wp_kernel<<<(OUTD * DD + 255) / 256, 256, 0, stream>>>(Wp, WpB);
    conv_kernel<<<(BB * SS) / TT, 256, 0, stream>>>(q, ks, v, Wk, bk, Abf);
    gemm_kernel<<<(BB * SS / BM) * (OUTD / BN), 256, 0, stream>>>(
        (const unsigned short*)Abf, (const unsigned short*)WpB, bp, out);
}

// Round 2
// 147.310 us; speedup vs baseline: 1.3387x; 1.3387x over previous
//
#include <hip/hip_runtime.h>
#include <hip/hip_bf16.h>

// Problem constants
#define BB 16
#define SS 1024
#define DD 384
#define HH 6
#define HDD 64
#define KK 9
#define KH 54      // K*H
#define NP 64      // KH padded to 64 for MFMA
#define OUTD 384
#define DKS 56     // dk row stride (f32)

typedef __attribute__((ext_vector_type(4))) float floatx4;
typedef __attribute__((ext_vector_type(8))) __bf16 bf16x8;
typedef __attribute__((ext_vector_type(4))) __bf16 bf16x4;
typedef __attribute__((ext_vector_type(2))) __bf16 bf16x2;

// ---------------------------------------------------------------------------
// Kernel 0: cast Wp -> bf16, Wk -> bf16 zero-padded to [64][384]
// ---------------------------------------------------------------------------
__global__ __launch_bounds__(256) void cast_kernel(const float* __restrict__ Wk,
                                                   const float* __restrict__ Wp,
                                                   __bf16* __restrict__ WkB,
                                                   __bf16* __restrict__ WpB) {
    int i = blockIdx.x * 256 + threadIdx.x;
    if (i < NP * DD) {
        int r = i / DD;
        WkB[i] = (r < KH) ? (__bf16)Wk[i] : (__bf16)0.0f;
    } else {
        int j = i - NP * DD;
        if (j < OUTD * DD) WpB[j] = (__bf16)Wp[j];
    }
}

// ---------------------------------------------------------------------------
// Kernel 1: logits = (q*ks) @ Wk^T + bk -> softmax over 9 taps -> dk
// MFMA 16x16x32 bf16. Block: 64 rows x 64(54) cols, 4 waves (16 rows each).
// ---------------------------------------------------------------------------
#define LBK 64
#define LLD 72   // LDS leading dim (bf16 elems): 144 B row -> 2-way max (free)

__global__ __launch_bounds__(256) void logits_kernel(const float* __restrict__ q,
                                                     const float* __restrict__ ks,
                                                     const __bf16* __restrict__ WkB,
                                                     const float* __restrict__ bk,
                                                     float* __restrict__ dkG) {
    __shared__ __bf16 qkS[64 * LLD];    // 9216 B
    __shared__ __bf16 WkS[NP * LLD];    // 9216 B
    __shared__ float  lgS[64 * 66];     // 16896 B

    const int tid  = threadIdx.x;
    const int wave = tid >> 6;
    const int lane = tid & 63;
    const int m0   = blockIdx.x * 64;

    const int wm = wave * 16;
    const int fr = lane & 15;
    const int fk = (lane >> 4) * 8;

    floatx4 acc[4] = {};

    const int sr = tid >> 2;            // staging row 0..63
    const int sc = (tid & 3) * 16;      // staging col base

    for (int k0 = 0; k0 < DD; k0 += LBK) {
        // stage qk = q*ks as bf16: 64 rows x 64 cols
        const float* qp = q  + (size_t)(m0 + sr) * DD + k0 + sc;
        const float* kp = ks + (size_t)(m0 + sr) * DD + k0 + sc;
#pragma unroll
        for (int c = 0; c < 16; c += 4) {
            floatx4 qv = *reinterpret_cast<const floatx4*>(qp + c);
            floatx4 kv = *reinterpret_cast<const floatx4*>(kp + c);
            floatx4 p = qv * kv;
            bf16x4 pk = { (__bf16)p.x, (__bf16)p.y, (__bf16)p.z, (__bf16)p.w };
            *reinterpret_cast<bf16x4*>(&qkS[sr * LLD + sc + c]) = pk;
        }
        // stage Wk tile: 64 rows x 64 cols bf16
#pragma unroll
        for (int c = 0; c < 16; c += 8) {
            *reinterpret_cast<bf16x8*>(&WkS[sr * LLD + sc + c]) =
                *reinterpret_cast<const bf16x8*>(WkB + (size_t)sr * DD + k0 + sc + c);
        }
        __syncthreads();

#pragma unroll
        for (int kk = 0; kk < LBK; kk += 32) {
            bf16x8 afrag = *reinterpret_cast<const bf16x8*>(&qkS[(wm + fr) * LLD + kk + fk]);
#pragma unroll
            for (int j = 0; j < 4; ++j) {
                bf16x8 bfrag = *reinterpret_cast<const bf16x8*>(&WkS[(j * 16 + fr) * LLD + kk + fk]);
                acc[j] = __builtin_amdgcn_mfma_f32_16x16x32_bf16(afrag, bfrag, acc[j], 0, 0, 0);
            }
        }
        __syncthreads();
    }

    // write logits to LDS (C/D layout: col=lane&15, row=(lane>>4)*4+reg)
    const int col_in = lane & 15;
    const int rgrp   = (lane >> 4) * 4;
#pragma unroll
    for (int j = 0; j < 4; ++j)
#pragma unroll
        for (int r = 0; r < 4; ++r)
            lgS[(wm + rgrp + r) * 66 + j * 16 + col_in] = acc[j][r];
    __syncthreads();

    // softmax over 9 taps: (row, head) pairs = 64*6 = 384
    for (int p = tid; p < 64 * HH; p += 256) {
        int row = p / HH, h = p % HH;
        float lg[KK];
        float mx = -1e30f;
#pragma unroll
        for (int k = 0; k < KK; ++k) {
            float s = lgS[row * 66 + h * KK + k] + bk[h * KK + k];
            lg[k] = s;
            mx = fmaxf(mx, s);
        }
        float sum = 0.0f;
#pragma unroll
        for (int k = 0; k < KK; ++k) { lg[k] = __expf(lg[k] - mx); sum += lg[k]; }
        float inv = 1.0f / sum;
        float* drow = dkG + (size_t)(m0 + row) * DKS + h * KK;
#pragma unroll
        for (int k = 0; k < KK; ++k) drow[k] = lg[k] * inv;
    }
}

// ---------------------------------------------------------------------------
// Kernel 2: 9-tap dynamic conv: A[b,s,d] = sum_k v[b, s-4+k, d] * dk[b,s,h(d),k]
// Block: 16 seq rows, float2-vectorized. Writes bf16 A.
// ---------------------------------------------------------------------------
#define CT 16

__global__ __launch_bounds__(256) void conv_kernel(const float* __restrict__ v,
                                                   const float* __restrict__ dkG,
                                                   __bf16* __restrict__ outA) {
    __shared__ float winS[(CT + 8) * DD];   // 36864 B
    __shared__ float dkS[CT * DKS];         // 3584 B

    const int blk = blockIdx.x;
    const int b   = blk / (SS / CT);
    const int s0  = (blk % (SS / CT)) * CT;
    const int tid = threadIdx.x;
    const size_t bs0 = (size_t)b * SS + s0;

    // stage v window rows s0-4 .. s0+19 (zero-padded), float4
    const float* vb = v + (size_t)b * SS * DD;
    for (int i = tid * 4; i < (CT + 8) * DD; i += 256 * 4) {
        int row = i / DD;
        int r = s0 - 4 + row;
        floatx4 val = {};
        if (r >= 0 && r < SS)
            val = *reinterpret_cast<const floatx4*>(vb + (size_t)r * DD + (i % DD));
        *reinterpret_cast<floatx4*>(&winS[i]) = val;
    }
    // stage dk rows
    for (int j = tid; j < CT * DKS; j += 256) dkS[j] = dkG[bs0 * DKS + j];
    __syncthreads();

    // compute: pairs of d
    const float2* win2 = reinterpret_cast<const float2*>(winS);
    for (int p = tid; p < CT * (DD / 2); p += 256) {
        int t = p / (DD / 2), dp = p % (DD / 2);
        int d = dp * 2, h = d >> 6;
        float ax = 0.0f, ay = 0.0f;
#pragma unroll
        for (int k = 0; k < KK; ++k) {
            float2 w = win2[(t + k) * (DD / 2) + dp];
            float dv = dkS[t * DKS + h * KK + k];
            ax += w.x * dv;
            ay += w.y * dv;
        }
        bf16x2 o = { (__bf16)ax, (__bf16)ay };
        *reinterpret_cast<bf16x2*>(&outA[(bs0 + t) * DD + d]) = o;
    }
}

// ---------------------------------------------------------------------------
// Kernel 3: C[16384][384] = A(bf16) @ Wp^T(bf16) + bp, fp32 out
// 128x64 tile, BK=64, 4 waves (2x2), mfma_f32_16x16x32_bf16
// ---------------------------------------------------------------------------
#define BM 128
#define BN 64
#define BK 64
#define GLD 72

__global__ __launch_bounds__(256) void gemm_kernel(const __bf16* __restrict__ A,
                                                   const __bf16* __restrict__ Bw,
                                                   const float* __restrict__ bias,
                                                   float* __restrict__ Cout) {
    __shared__ __bf16 As[BM * GLD];   // 18432 B
    __shared__ __bf16 Bs[BN * GLD];   //  9216 B

    const int tid  = threadIdx.x;
    const int wave = tid >> 6;
    const int lane = tid & 63;

    const int mtile = blockIdx.x / (OUTD / BN);
    const int ntile = blockIdx.x % (OUTD / BN);
    const int m0 = mtile * BM;
    const int n0 = ntile * BN;

    const int wm = (wave >> 1) * 64;
    const int wn = (wave & 1) * 32;

    floatx4 acc[4][2] = {};

    const int fr = lane & 15;
    const int fk = (lane >> 4) * 8;

    for (int k0 = 0; k0 < DD; k0 += BK) {
        // stage A: 128x64 bf16, 4 passes of 16B/thread
#pragma unroll
        for (int p = 0; p < 4; ++p) {
            int idx = tid + p * 256;
            int r = idx >> 3, c = (idx & 7) * 8;
            *reinterpret_cast<bf16x8*>(&As[r * GLD + c]) =
                *reinterpret_cast<const bf16x8*>(A + (size_t)(m0 + r) * DD + k0 + c);
        }
        // stage B: 64x64 bf16, 2 passes
#pragma unroll
        for (int p = 0; p < 2; ++p) {
            int idx = tid + p * 256;
            int r = idx >> 3, c = (idx & 7) * 8;
            *reinterpret_cast<bf16x8*>(&Bs[r * GLD + c]) =
                *reinterpret_cast<const bf16x8*>(Bw + (size_t)(n0 + r) * DD + k0 + c);
        }
        __syncthreads();

#pragma unroll
        for (int kk = 0; kk < BK; kk += 32) {
            bf16x8 bfrag[2];
#pragma unroll
            for (int j = 0; j < 2; ++j)
                bfrag[j] = *reinterpret_cast<const bf16x8*>(&Bs[(wn + j * 16 + fr) * GLD + kk + fk]);
#pragma unroll
            for (int i = 0; i < 4; ++i) {
                bf16x8 afrag = *reinterpret_cast<const bf16x8*>(&As[(wm + i * 16 + fr) * GLD + kk + fk]);
#pragma unroll
                for (int j = 0; j < 2; ++j)
                    acc[i][j] = __builtin_amdgcn_mfma_f32_16x16x32_bf16(afrag, bfrag[j], acc[i][j], 0, 0, 0);
            }
        }
        __syncthreads();
    }

    const int col_in = lane & 15;
    const int rgrp   = (lane >> 4) * 4;
#pragma unroll
    for (int i = 0; i < 4; ++i) {
#pragma unroll
        for (int j = 0; j < 2; ++j) {
            int col = n0 + wn + j * 16 + col_in;
            float bv = bias[col];
#pragma unroll
            for (int r = 0; r < 4; ++r) {
                int row = m0 + wm + i * 16 + rgrp + r;
                Cout[(size_t)row * OUTD + col] = acc[i][j][r] + bv;
            }
        }
    }
}

// ---------------------------------------------------------------------------
extern "C" void kernel_launch(void* const* d_in, const int* in_sizes, int n_in,
                              void* d_out, int out_size, void* d_ws, size_t ws_size,
                              hipStream_t stream) {
    const float* q  = (const float*)d_in[0];
    const float* ks = (const float*)d_in[1];
    const float* v  = (const float*)d_in[2];
    const float* Wk = (const float*)d_in[3];
    const float* bk = (const float*)d_in[4];
    const float* Wp = (const float*)d_in[5];
    const float* bp = (const float*)d_in[6];
    float* out = (float*)d_out;

    // ws layout: WpB bf16 294912 B | WkB bf16 49152 B | dk f32 3670016 B | A bf16 12582912 B
    __bf16* WpB = (__bf16*)d_ws;
    __bf16* WkB = (__bf16*)((char*)d_ws + 294912);
    float*  dkG = (float*)((char*)d_ws + 294912 + 49152);
    __bf16* Abf = (__bf16*)((char*)d_ws + 294912 + 49152 + 3670016);

    cast_kernel<<<(NP * DD + OUTD * DD + 255) / 256, 256, 0, stream>>>(Wk, Wp, WkB, WpB);
    logits_kernel<<<(BB * SS) / 64, 256, 0, stream>>>(q, ks, WkB, bk, dkG);
    conv_kernel<<<(BB * SS) / CT, 256, 0, stream>>>(v, dkG, Abf);
    gemm_kernel<<<(BB * SS / BM) * (OUTD / BN), 256, 0, stream>>>(Abf, WpB, bp, out);
}